// Round 1
// baseline (977.087 us; speedup 1.0000x reference)
//
#include <hip/hip_runtime.h>
#include <math.h>

// Problem constants
#define BB 1024        // batch
#define DD 128         // feature dim
#define QQ 65536       // queue length == queue_new length
#define BM 8           // rows per block
#define NJ 4           // queue cols per lane per outer iter
#define THREADS 256
#define JSLICES 8      // queue slices
#define JS (QQ / JSLICES)   // 8192
#define NSTAT 5        // tot, neg, ps, npos, srr

__global__ __launch_bounds__(THREADS)
void supcon_partial(const float* __restrict__ features,
                    const int*   __restrict__ labels,
                    const float* __restrict__ queue,
                    const int*   __restrict__ queue_labels,
                    float* __restrict__ stats)
{
    __shared__ float f2s[BM][DD];          // 4 KB
    __shared__ int   lab_s[BM];
    __shared__ float red[4][BM][NSTAT];    // cross-wave reduce

    const int bid   = blockIdx.x;
    const int rtile = bid >> 3;            // / JSLICES
    const int slice = bid & (JSLICES - 1);
    const int rbase = rtile * BM;
    const int tid   = threadIdx.x;

    // stage f2 tile (features[r,1,:]) into LDS, coalesced float4
    {
        int idx = tid;                      // BM*DD/4 == 256 == THREADS
        int r  = idx >> 5;                  // / 32
        int k4 = idx & 31;
        const float4* src = reinterpret_cast<const float4*>(
            features + (size_t)(rbase + r) * 2 * DD + DD);
        reinterpret_cast<float4*>(&f2s[r][0])[k4] = src[k4];
    }
    if (tid < BM) lab_s[tid] = labels[rbase + tid];
    __syncthreads();

    int mylab[BM];
#pragma unroll
    for (int r = 0; r < BM; ++r) mylab[r] = lab_s[r];

    float tot[BM], neg[BM], ps[BM], np[BM], sr[BM];
#pragma unroll
    for (int r = 0; r < BM; ++r) { tot[r]=0.f; neg[r]=0.f; ps[r]=0.f; np[r]=0.f; sr[r]=0.f; }

    const float invT = 1.0f / 0.07f;
    const int jbase0 = slice * JS;

    for (int it = 0; it < JS / (THREADS * NJ); ++it) {   // 8 iters
        int   js_[NJ];
        const float* qrows[NJ];
        int   qlabs[NJ];
#pragma unroll
        for (int u = 0; u < NJ; ++u) {
            int j = jbase0 + it * (THREADS * NJ) + u * THREADS + tid;
            js_[u] = j;
            // queue_new[j] = f1[j] (= features[j,0,:]) for j < B, else queue[j-B]
            qrows[u] = (j < BB) ? (features + (size_t)j * 2 * DD)
                                : (queue    + (size_t)(j - BB) * DD);
            qlabs[u] = (j < BB) ? labels[j] : queue_labels[j - BB];
        }

        float acc[NJ][BM];
#pragma unroll
        for (int u = 0; u < NJ; ++u)
#pragma unroll
            for (int r = 0; r < BM; ++r) acc[u][r] = 0.f;

        for (int k4 = 0; k4 < DD / 4; ++k4) {
            float4 qv[NJ];
#pragma unroll
            for (int u = 0; u < NJ; ++u)
                qv[u] = reinterpret_cast<const float4*>(qrows[u])[k4];
#pragma unroll
            for (int r = 0; r < BM; ++r) {
                float4 fv = reinterpret_cast<const float4*>(&f2s[r][0])[k4];
#pragma unroll
                for (int u = 0; u < NJ; ++u) {
                    acc[u][r] = fmaf(fv.x, qv[u].x, acc[u][r]);
                    acc[u][r] = fmaf(fv.y, qv[u].y, acc[u][r]);
                    acc[u][r] = fmaf(fv.z, qv[u].z, acc[u][r]);
                    acc[u][r] = fmaf(fv.w, qv[u].w, acc[u][r]);
                }
            }
        }

#pragma unroll
        for (int u = 0; u < NJ; ++u) {
#pragma unroll
            for (int r = 0; r < BM; ++r) {
                float s = acc[u][r] * invT;
                float e = __expf(s);
                bool ispos = (qlabs[u] == mylab[r]);
                bool diag  = (js_[u] == rbase + r);
                tot[r] += e;
                neg[r] += ispos ? 0.f : e;
                ps[r]  += (ispos && !diag) ? s   : 0.f;
                np[r]  += (ispos && !diag) ? 1.f : 0.f;
                sr[r]  += diag ? s : 0.f;   // exactly one contributor grid-wide
            }
        }
    }

    // wave butterfly reduce (64 lanes), all stats are plain sums
#pragma unroll
    for (int r = 0; r < BM; ++r) {
#pragma unroll
        for (int off = 32; off > 0; off >>= 1) {
            tot[r] += __shfl_xor(tot[r], off);
            neg[r] += __shfl_xor(neg[r], off);
            ps[r]  += __shfl_xor(ps[r],  off);
            np[r]  += __shfl_xor(np[r],  off);
            sr[r]  += __shfl_xor(sr[r],  off);
        }
    }
    const int wid = tid >> 6, lane = tid & 63;
    if (lane == 0) {
#pragma unroll
        for (int r = 0; r < BM; ++r) {
            red[wid][r][0] = tot[r]; red[wid][r][1] = neg[r];
            red[wid][r][2] = ps[r];  red[wid][r][3] = np[r];
            red[wid][r][4] = sr[r];
        }
    }
    __syncthreads();
    if (tid < BM) {
        int r = tid;
        float t=0.f, n=0.f, p=0.f, c=0.f, s=0.f;
#pragma unroll
        for (int w = 0; w < 4; ++w) {
            t += red[w][r][0]; n += red[w][r][1]; p += red[w][r][2];
            c += red[w][r][3]; s += red[w][r][4];
        }
        float* dst = stats + ((size_t)(rbase + r) * JSLICES + slice) * NSTAT;
        dst[0]=t; dst[1]=n; dst[2]=p; dst[3]=c; dst[4]=s;
    }
}

__global__ __launch_bounds__(1024)
void supcon_final(const float* __restrict__ stats, float* __restrict__ out)
{
    const int r = threadIdx.x;
    float tot=0.f, neg=0.f, ps=0.f, np=0.f, sr=0.f;
#pragma unroll
    for (int s = 0; s < JSLICES; ++s) {
        const float* st = stats + ((size_t)r * JSLICES + s) * NSTAT;
        tot += st[0]; neg += st[1]; ps += st[2]; np += st[3]; sr += st[4];
    }
    // triplet = s_rr - log(sum_{j!=r} e^s) ; mlpp = ps/np - log(neg_sum)
    float err     = __expf(sr);
    float triplet = sr - logf(tot - err);
    float mlpp    = ps / np - logf(neg);

    __shared__ float s1[1024], s2[1024];
    s1[r] = -triplet;
    s2[r] = -mlpp;
    __syncthreads();
    for (int off = 512; off > 0; off >>= 1) {
        if (r < off) { s1[r] += s1[r + off]; s2[r] += s2[r + off]; }
        __syncthreads();
    }
    if (r == 0) {
        float selfl  = s1[0] / (float)BB;
        float classl = s2[0] / (float)BB;
        out[0] = 0.5f * (selfl + classl);  // loss
        out[1] = selfl;                    // self_loss
        out[2] = classl;                   // class_loss
    }
}

extern "C" void kernel_launch(void* const* d_in, const int* in_sizes, int n_in,
                              void* d_out, int out_size, void* d_ws, size_t ws_size,
                              hipStream_t stream)
{
    const float* features     = (const float*)d_in[0];
    const int*   labels       = (const int*)  d_in[1];
    const float* queue        = (const float*)d_in[2];
    const int*   queue_labels = (const int*)  d_in[3];
    float* stats = (float*)d_ws;   // 1024 * 8 * 5 * 4B = 160 KB

    supcon_partial<<<dim3(BB / BM * JSLICES), dim3(THREADS), 0, stream>>>(
        features, labels, queue, queue_labels, stats);
    supcon_final<<<dim3(1), dim3(1024), 0, stream>>>(stats, (float*)d_out);
}

// Round 2
// 125.415 us; speedup vs baseline: 7.7908x; 7.7908x over previous
//
#include <hip/hip_runtime.h>
#include <math.h>

#define BB 1024
#define DD 128
#define QQ 65536
#define CHUNK 32
#define THREADS 256
#define COLS_PER_BLOCK 128          // 4 waves x 32 cols
#define F2G (BB / COLS_PER_BLOCK)   // 8
#define NSTAT 5

typedef short short8 __attribute__((ext_vector_type(8)));   // bf16x8 frag (4 VGPR)
typedef float f32x4  __attribute__((ext_vector_type(4)));   // acc frag

static __device__ __forceinline__ short bf16rne(float f) {
    union { float f; unsigned u; } v; v.f = f;
    unsigned r = (v.u + 0x7FFFu + ((v.u >> 16) & 1u)) >> 16;
    return (short)r;
}

static __device__ __forceinline__ short8 pack8(float4 x, float4 y) {
    short8 r;
    r[0]=bf16rne(x.x); r[1]=bf16rne(x.y); r[2]=bf16rne(x.z); r[3]=bf16rne(x.w);
    r[4]=bf16rne(y.x); r[5]=bf16rne(y.y); r[6]=bf16rne(y.z); r[7]=bf16rne(y.w);
    return r;
}

// stats layout: stats[row][slice][5] : tot, neg, ps, np, sr
__global__ __launch_bounds__(THREADS)
void supcon_mfma(const float* __restrict__ features,
                 const int*   __restrict__ labels,
                 const float* __restrict__ queue,
                 const int*   __restrict__ queue_labels,
                 float* __restrict__ stats, int nslices)
{
    __shared__ int4 ldsbuf[2][512];   // 2 x 8KB bf16 A-chunks [32 rows][128 k], XOR-swizzled

    const int tid = threadIdx.x;
    const int l   = tid & 63;
    const int w   = tid >> 6;
    const int bid = blockIdx.x;
    const int slice = bid % nslices;
    const int f2g   = bid / nslices;
    const int sliceRows = QQ / nslices;
    const int nchunks   = sliceRows / CHUNK;
    const int colbase   = f2g * COLS_PER_BLOCK + w * 32;
    const float invT = 1.0f / 0.07f;

    // ---- stationary B operand: f2 rows (= output cols), bf16 frags in regs ----
    short8 bf[2][4];
    int mylab[2], myrow[2];
#pragma unroll
    for (int b = 0; b < 2; ++b) {
        int r = colbase + b * 16 + (l & 15);
        myrow[b] = r;
        mylab[b] = labels[r];
        const float* fp = features + (size_t)r * 2 * DD + DD + ((l >> 4) * 8);
#pragma unroll
        for (int kk = 0; kk < 4; ++kk) {
            float4 x = *reinterpret_cast<const float4*>(fp + kk * 32);
            float4 y = *reinterpret_cast<const float4*>(fp + kk * 32 + 4);
            bf[b][kk] = pack8(x, y);
        }
    }

    float tot[2] = {0.f, 0.f}, neg[2] = {0.f, 0.f}, ps[2] = {0.f, 0.f};
    float np[2]  = {0.f, 0.f}, sr[2]  = {0.f, 0.f};

    // staging thread map: row = tid>>3 (0..31), seg = tid&7 (16 floats each)
    const int srow = tid >> 3;
    const int sseg = tid & 7;
    const int swzs = (srow & 7) << 4;
    const int j0base = slice * sliceRows;

    // prologue: stage chunk 0 into buf 0
    {
        int j = j0base + srow;
        const float* src = (j < BB) ? (features + (size_t)j * 2 * DD)
                                    : (queue    + (size_t)(j - BB) * DD);
        src += sseg * 16;
        float4 p0 = reinterpret_cast<const float4*>(src)[0];
        float4 p1 = reinterpret_cast<const float4*>(src)[1];
        float4 p2 = reinterpret_cast<const float4*>(src)[2];
        float4 p3 = reinterpret_cast<const float4*>(src)[3];
        short8 lo = pack8(p0, p1), hi = pack8(p2, p3);
        char* base = (char*)&ldsbuf[0][0] + srow * 256;
        int cb0 = (sseg * 32) ^ swzs;
        *reinterpret_cast<short8*>(base + cb0)        = lo;
        *reinterpret_cast<short8*>(base + (cb0 ^ 16)) = hi;
    }

    int cur = 0;
    for (int c = 0; c < nchunks; ++c) {
        __syncthreads();
        const int cj0 = j0base + c * CHUNK;

        // T14: issue next chunk's global loads early
        float4 p0, p1, p2, p3;
        const bool havenext = (c + 1 < nchunks);
        if (havenext) {
            int j = cj0 + CHUNK + srow;
            const float* src = (j < BB) ? (features + (size_t)j * 2 * DD)
                                        : (queue    + (size_t)(j - BB) * DD);
            src += sseg * 16;
            p0 = reinterpret_cast<const float4*>(src)[0];
            p1 = reinterpret_cast<const float4*>(src)[1];
            p2 = reinterpret_cast<const float4*>(src)[2];
            p3 = reinterpret_cast<const float4*>(src)[3];
        }

        // compute from buf[cur]
        const char* abase = (const char*)&ldsbuf[cur][0];
#pragma unroll
        for (int t = 0; t < 2; ++t) {
            const int row = t * 16 + (l & 15);
            const char* rbase = abase + row * 256;
            const int g16 = (l >> 4) * 16;
            const int swz = (row & 7) << 4;
            short8 a[4];
#pragma unroll
            for (int kk = 0; kk < 4; ++kk)
                a[kk] = *reinterpret_cast<const short8*>(rbase + ((kk * 64 + g16) ^ swz));

            const int j0 = cj0 + t * 16 + ((l >> 4) << 2);
            int4 ql4 = (j0 < BB) ? *reinterpret_cast<const int4*>(labels + j0)
                                 : *reinterpret_cast<const int4*>(queue_labels + (j0 - BB));
            const int* ql = reinterpret_cast<const int*>(&ql4);

#pragma unroll
            for (int b = 0; b < 2; ++b) {
                f32x4 acc = {0.f, 0.f, 0.f, 0.f};
#pragma unroll
                for (int kk = 0; kk < 4; ++kk)
                    acc = __builtin_amdgcn_mfma_f32_16x16x32_bf16(a[kk], bf[b][kk], acc, 0, 0, 0);
#pragma unroll
                for (int reg = 0; reg < 4; ++reg) {
                    float s = acc[reg] * invT;
                    float e = __expf(s);
                    int j = j0 + reg;
                    bool pos = (ql[reg] == mylab[b]);
                    bool dg  = (j == myrow[b]);
                    bool pp  = pos && !dg;
                    tot[b] += e;
                    neg[b] += pos ? 0.f : e;
                    ps[b]  += pp ? s : 0.f;
                    np[b]  += pp ? 1.f : 0.f;
                    sr[b]  += dg ? s : 0.f;
                }
            }
        }

        // write next chunk into the other buffer (after compute; loads have landed)
        if (havenext) {
            short8 lo = pack8(p0, p1), hi = pack8(p2, p3);
            char* base = (char*)&ldsbuf[cur ^ 1][0] + srow * 256;
            int cb0 = (sseg * 32) ^ swzs;
            *reinterpret_cast<short8*>(base + cb0)        = lo;
            *reinterpret_cast<short8*>(base + (cb0 ^ 16)) = hi;
            cur ^= 1;
        }
    }

    // reduce across the 4 lane-groups sharing each output col
#pragma unroll
    for (int b = 0; b < 2; ++b) {
#pragma unroll
        for (int off = 16; off <= 32; off <<= 1) {
            tot[b] += __shfl_xor(tot[b], off);
            neg[b] += __shfl_xor(neg[b], off);
            ps[b]  += __shfl_xor(ps[b],  off);
            np[b]  += __shfl_xor(np[b],  off);
            sr[b]  += __shfl_xor(sr[b],  off);
        }
    }
    if ((l >> 4) == 0) {
#pragma unroll
        for (int b = 0; b < 2; ++b) {
            float* dst = stats + ((size_t)(colbase + b * 16 + l) * nslices + slice) * NSTAT;
            dst[0] = tot[b]; dst[1] = neg[b]; dst[2] = ps[b]; dst[3] = np[b]; dst[4] = sr[b];
        }
    }
}

__global__ __launch_bounds__(1024)
void supcon_final(const float* __restrict__ stats, float* __restrict__ out, int nslices)
{
    const int r = threadIdx.x;
    float tot = 0.f, neg = 0.f, ps = 0.f, np = 0.f, sr = 0.f;
    for (int s = 0; s < nslices; ++s) {
        const float* st = stats + ((size_t)r * nslices + s) * NSTAT;
        tot += st[0]; neg += st[1]; ps += st[2]; np += st[3]; sr += st[4];
    }
    float err     = __expf(sr);
    float triplet = sr - logf(tot - err);
    float mlpp    = ps / np - logf(neg);

    __shared__ float s1[1024], s2[1024];
    s1[r] = -triplet;
    s2[r] = -mlpp;
    __syncthreads();
    for (int off = 512; off > 0; off >>= 1) {
        if (r < off) { s1[r] += s1[r + off]; s2[r] += s2[r + off]; }
        __syncthreads();
    }
    if (r == 0) {
        float selfl  = s1[0] / (float)BB;
        float classl = s2[0] / (float)BB;
        out[0] = 0.5f * (selfl + classl);
        out[1] = selfl;
        out[2] = classl;
    }
}

extern "C" void kernel_launch(void* const* d_in, const int* in_sizes, int n_in,
                              void* d_out, int out_size, void* d_ws, size_t ws_size,
                              hipStream_t stream)
{
    const float* features     = (const float*)d_in[0];
    const int*   labels       = (const int*)  d_in[1];
    const float* queue        = (const float*)d_in[2];
    const int*   queue_labels = (const int*)  d_in[3];

    int nslices = 32;
    while ((size_t)BB * nslices * NSTAT * sizeof(float) > ws_size && nslices > 1)
        nslices >>= 1;
    float* stats = (float*)d_ws;

    supcon_mfma<<<dim3(F2G * nslices), dim3(THREADS), 0, stream>>>(
        features, labels, queue, queue_labels, stats, nslices);
    supcon_final<<<dim3(1), dim3(1024), 0, stream>>>(stats, (float*)d_out, nslices);
}

// Round 3
// 114.694 us; speedup vs baseline: 8.5191x; 1.0935x over previous
//
#include <hip/hip_runtime.h>
#include <math.h>

#define BB 1024
#define DD 128
#define QQ 65536
#define CHUNK 32
#define THREADS 256
#define COLS_PER_BLOCK 256
#define F2G (BB / COLS_PER_BLOCK)   // 4
#define NSLICES 256
#define INV_T 14.285714285714286f
#define SCALE 20.609929155556627f   // (1/T) * log2(e)

typedef short short8 __attribute__((ext_vector_type(8)));
typedef float f32x4  __attribute__((ext_vector_type(4)));

static __device__ __forceinline__ unsigned short bf16rne(float f) {
    union { float f; unsigned u; } v; v.f = f;
    unsigned r = (v.u + 0x7FFFu + ((v.u >> 16) & 1u)) >> 16;
    return (unsigned short)r;
}

static __device__ __forceinline__ short8 pack8s(float4 x, float4 y) { // scaled
    short8 r;
    r[0]=(short)bf16rne(x.x*SCALE); r[1]=(short)bf16rne(x.y*SCALE);
    r[2]=(short)bf16rne(x.z*SCALE); r[3]=(short)bf16rne(x.w*SCALE);
    r[4]=(short)bf16rne(y.x*SCALE); r[5]=(short)bf16rne(y.y*SCALE);
    r[6]=(short)bf16rne(y.z*SCALE); r[7]=(short)bf16rne(y.w*SCALE);
    return r;
}
static __device__ __forceinline__ short8 pack8(float4 x, float4 y) { // unscaled
    short8 r;
    r[0]=(short)bf16rne(x.x); r[1]=(short)bf16rne(x.y);
    r[2]=(short)bf16rne(x.z); r[3]=(short)bf16rne(x.w);
    r[4]=(short)bf16rne(y.x); r[5]=(short)bf16rne(y.y);
    r[6]=(short)bf16rne(y.z); r[7]=(short)bf16rne(y.w);
    return r;
}

// ---------- K0: cnt histogram, fsum scatter, srr dots, f2bf(scaled bf16) ----------
__global__ __launch_bounds__(256)
void k0_prep(const float* __restrict__ features, const int* __restrict__ labels,
             const int* __restrict__ queue_labels,
             float* __restrict__ fsum, int* __restrict__ cnt,
             float* __restrict__ srr, unsigned short* f2bf)
{
    int t = blockIdx.x * 256 + threadIdx.x;          // grid 256x256 = 65536
    // histogram over qlab_new[t]
    {
        int lab = (t < BB) ? labels[t] : queue_labels[t - BB];
        atomicAdd(&cnt[lab], 1);
    }
    // one wave per batch row
    int r = t >> 6, lane = t & 63;                   // r in [0,1024)
    float2 a = reinterpret_cast<const float2*>(features + (size_t)r * 2 * DD + DD)[lane];
    float2 b = reinterpret_cast<const float2*>(features + (size_t)r * 2 * DD)[lane];
    float p = a.x * b.x + a.y * b.y;
#pragma unroll
    for (int off = 32; off > 0; off >>= 1) p += __shfl_xor(p, off);
    if (lane == 0) srr[r] = p;
    int lab = labels[r];
    atomicAdd(&fsum[(size_t)lab * DD + 2 * lane],     a.x);
    atomicAdd(&fsum[(size_t)lab * DD + 2 * lane + 1], a.y);
    if (f2bf) {
        unsigned int packed = (unsigned int)bf16rne(a.x * SCALE)
                            | ((unsigned int)bf16rne(a.y * SCALE) << 16);
        reinterpret_cast<unsigned int*>(f2bf)[(size_t)r * (DD / 2) + lane] = packed;
    }
}

// ---------- K1: gather-dot (class term) + qbf/qlabn prebuild ----------
template<int PRE>
__global__ __launch_bounds__(256)
void k1_gather(const float* __restrict__ features, const int* __restrict__ labels,
               const float* __restrict__ queue, const int* __restrict__ queue_labels,
               const float* __restrict__ fsum, const int* __restrict__ cnt,
               unsigned short* __restrict__ qbf, int* __restrict__ qlabn,
               float* __restrict__ S1)
{
    int t = blockIdx.x * 256 + threadIdx.x;
    int wid = t >> 6, lane = t & 63;                 // 1024 waves, 64 rows each
    float acc = 0.f;
    for (int it = 0; it < QQ / 1024; ++it) {
        int j = wid * (QQ / 1024) + it;
        int lab = (j < BB) ? labels[j] : queue_labels[j - BB];
        const float* src = (j < BB) ? (features + (size_t)j * 2 * DD)
                                    : (queue + (size_t)(j - BB) * DD);
        float2 v = reinterpret_cast<const float2*>(src)[lane];
        if (PRE) {
            unsigned int packed = (unsigned int)bf16rne(v.x)
                                | ((unsigned int)bf16rne(v.y) << 16);
            reinterpret_cast<unsigned int*>(qbf)[(size_t)j * (DD / 2) + lane] = packed;
            if (lane == 0) qlabn[j] = lab;
        }
        float2 f = reinterpret_cast<const float2*>(fsum + (size_t)lab * DD)[lane];
        float w = 1.f / (float)(cnt[lab] - 1);
        acc += w * (v.x * f.x + v.y * f.y);
    }
#pragma unroll
    for (int off = 32; off > 0; off >>= 1) acc += __shfl_xor(acc, off);
    if (lane == 0) atomicAdd(S1, acc);
}

// ---------- main: tot/pose via MFMA, stats[col][slice][2] ----------
template<int PRE>
__global__ __launch_bounds__(THREADS)
void supcon_main(const float* __restrict__ features, const int* __restrict__ labels,
                 const float* __restrict__ queue, const int* __restrict__ queue_labels,
                 const unsigned short* __restrict__ qbf, const int* __restrict__ qlabn,
                 const unsigned short* __restrict__ f2bf,
                 float* __restrict__ stats, int nslices)
{
    __shared__ int4 ldsbuf[2][512];   // 2 x 8KB bf16 A-chunks [32][128], swizzled

    const int tid = threadIdx.x;
    const int l = tid & 63, w = tid >> 6;
    const int bid = blockIdx.x;
    const int slice = bid % nslices, f2g = bid / nslices;
    const int sliceRows = QQ / nslices;
    const int nchunks = sliceRows / CHUNK;
    const int colbase = f2g * COLS_PER_BLOCK + w * 64;

    // stationary B operand: 4x16 f2 cols, pre-scaled bf16
    short8 bf[4][4];
    int mylab[4];
#pragma unroll
    for (int b = 0; b < 4; ++b) {
        int r = colbase + b * 16 + (l & 15);
        mylab[b] = labels[r];
        if (PRE) {
            const unsigned short* fp = f2bf + (size_t)r * DD + ((l >> 4) * 8);
#pragma unroll
            for (int kk = 0; kk < 4; ++kk)
                bf[b][kk] = *reinterpret_cast<const short8*>(fp + kk * 32);
        } else {
            const float* fp = features + (size_t)r * 2 * DD + DD + ((l >> 4) * 8);
#pragma unroll
            for (int kk = 0; kk < 4; ++kk) {
                float4 x = *reinterpret_cast<const float4*>(fp + kk * 32);
                float4 y = *reinterpret_cast<const float4*>(fp + kk * 32 + 4);
                bf[b][kk] = pack8s(x, y);
            }
        }
    }

    float tot[4] = {0.f,0.f,0.f,0.f}, pose[4] = {0.f,0.f,0.f,0.f};

    const int srow = tid >> 3, sseg = tid & 7;
    const int swzs = (srow & 7) << 4;
    const int j0base = slice * sliceRows;

    // prologue: stage chunk 0
    {
        int j = j0base + srow;
        char* base = (char*)&ldsbuf[0][0] + srow * 256;
        int cb0 = (sseg * 32) ^ swzs;
        if (PRE) {
            const short8* src = reinterpret_cast<const short8*>(
                qbf + (size_t)j * DD + sseg * 16);
            *reinterpret_cast<short8*>(base + cb0)        = src[0];
            *reinterpret_cast<short8*>(base + (cb0 ^ 16)) = src[1];
        } else {
            const float* src = ((j < BB) ? (features + (size_t)j * 2 * DD)
                                         : (queue + (size_t)(j - BB) * DD)) + sseg * 16;
            float4 p0 = reinterpret_cast<const float4*>(src)[0];
            float4 p1 = reinterpret_cast<const float4*>(src)[1];
            float4 p2 = reinterpret_cast<const float4*>(src)[2];
            float4 p3 = reinterpret_cast<const float4*>(src)[3];
            *reinterpret_cast<short8*>(base + cb0)        = pack8(p0, p1);
            *reinterpret_cast<short8*>(base + (cb0 ^ 16)) = pack8(p2, p3);
        }
    }

    int cur = 0;
    for (int c = 0; c < nchunks; ++c) {
        __syncthreads();
        const int cj0 = j0base + c * CHUNK;
        const bool havenext = (c + 1 < nchunks);

        // issue next chunk's loads early (T14)
        short8 nlo, nhi;
        float4 p0, p1, p2, p3;
        if (havenext) {
            int j = cj0 + CHUNK + srow;
            if (PRE) {
                const short8* src = reinterpret_cast<const short8*>(
                    qbf + (size_t)j * DD + sseg * 16);
                nlo = src[0]; nhi = src[1];
            } else {
                const float* src = ((j < BB) ? (features + (size_t)j * 2 * DD)
                                             : (queue + (size_t)(j - BB) * DD)) + sseg * 16;
                p0 = reinterpret_cast<const float4*>(src)[0];
                p1 = reinterpret_cast<const float4*>(src)[1];
                p2 = reinterpret_cast<const float4*>(src)[2];
                p3 = reinterpret_cast<const float4*>(src)[3];
            }
        }

        // compute from buf[cur]
        const char* abase = (const char*)&ldsbuf[cur][0];
#pragma unroll
        for (int t2 = 0; t2 < 2; ++t2) {
            const int row = t2 * 16 + (l & 15);
            const char* rbase = abase + row * 256;
            const int g16 = (l >> 4) * 16;
            const int swz = (row & 7) << 4;
            const int j0 = cj0 + t2 * 16 + ((l >> 4) << 2);

            int4 ql4;
            if (PRE) ql4 = *reinterpret_cast<const int4*>(qlabn + j0);
            else ql4 = (j0 < BB) ? *reinterpret_cast<const int4*>(labels + j0)
                                 : *reinterpret_cast<const int4*>(queue_labels + (j0 - BB));
            const int* ql = reinterpret_cast<const int*>(&ql4);

            f32x4 acc[4];
#pragma unroll
            for (int b = 0; b < 4; ++b) acc[b] = f32x4{0.f,0.f,0.f,0.f};
#pragma unroll
            for (int kk = 0; kk < 4; ++kk) {
                short8 a = *reinterpret_cast<const short8*>(rbase + ((kk * 64 + g16) ^ swz));
#pragma unroll
                for (int b = 0; b < 4; ++b)
                    acc[b] = __builtin_amdgcn_mfma_f32_16x16x32_bf16(a, bf[b][kk], acc[b], 0, 0, 0);
            }
#pragma unroll
            for (int b = 0; b < 4; ++b) {
#pragma unroll
                for (int reg = 0; reg < 4; ++reg) {
                    float e = exp2f(acc[b][reg]);      // acc is already s*log2(e)
                    tot[b] += e;
                    pose[b] += (ql[reg] == mylab[b]) ? e : 0.f;
                }
            }
        }

        // write next chunk into other buffer
        if (havenext) {
            char* base = (char*)&ldsbuf[cur ^ 1][0] + srow * 256;
            int cb0 = (sseg * 32) ^ swzs;
            if (PRE) {
                *reinterpret_cast<short8*>(base + cb0)        = nlo;
                *reinterpret_cast<short8*>(base + (cb0 ^ 16)) = nhi;
            } else {
                *reinterpret_cast<short8*>(base + cb0)        = pack8(p0, p1);
                *reinterpret_cast<short8*>(base + (cb0 ^ 16)) = pack8(p2, p3);
            }
            cur ^= 1;
        }
    }

#pragma unroll
    for (int b = 0; b < 4; ++b) {
#pragma unroll
        for (int off = 16; off <= 32; off <<= 1) {
            tot[b]  += __shfl_xor(tot[b],  off);
            pose[b] += __shfl_xor(pose[b], off);
        }
    }
    if ((l >> 4) == 0) {
#pragma unroll
        for (int b = 0; b < 4; ++b) {
            float2 v; v.x = tot[b]; v.y = pose[b];
            *reinterpret_cast<float2*>(
                stats + ((size_t)(colbase + b * 16 + l) * nslices + slice) * 2) = v;
        }
    }
}

// ---------- F1: per-row finish (log terms), accumulate scalars ----------
__global__ __launch_bounds__(256)
void f1_rows(const float* __restrict__ stats, const float* __restrict__ srr,
             const int* __restrict__ cnt, const int* __restrict__ labels,
             float* __restrict__ accums, int nslices)
{
    __shared__ float red[4][2];
    int wv = threadIdx.x >> 6, lane = threadIdx.x & 63;
    int r = blockIdx.x * 4 + wv;
    float tot = 0.f, pose = 0.f;
    for (int s = lane; s < nslices; s += 64) {
        float2 v = reinterpret_cast<const float2*>(stats)[(size_t)r * nslices + s];
        tot += v.x; pose += v.y;
    }
#pragma unroll
    for (int off = 32; off > 0; off >>= 1) {
        tot  += __shfl_xor(tot,  off);
        pose += __shfl_xor(pose, off);
    }
    if (lane == 0) {
        float neg  = tot - pose;
        float srow = srr[r] * INV_T;
        float err  = expf(srow);
        float trip = srow - logf(tot - err);
        int   npq  = cnt[labels[r]] - 1;
        float p2   = srow / (float)npq + logf(neg);
        red[wv][0] = trip; red[wv][1] = p2;
    }
    __syncthreads();
    if (threadIdx.x == 0) {
        atomicAdd(&accums[0], red[0][0] + red[1][0] + red[2][0] + red[3][0]);
        atomicAdd(&accums[1], red[0][1] + red[1][1] + red[2][1] + red[3][1]);
    }
}

__global__ void f2_out(const float* __restrict__ accums, const float* __restrict__ S1,
                       float* __restrict__ out)
{
    if (threadIdx.x == 0) {
        float accT = accums[0], accP = accums[1], s1 = *S1;
        float selfl  = -accT / (float)BB;
        float classl = (-s1 * INV_T + accP) / (float)BB;
        out[0] = 0.5f * (selfl + classl);
        out[1] = selfl;
        out[2] = classl;
    }
}

extern "C" void kernel_launch(void* const* d_in, const int* in_sizes, int n_in,
                              void* d_out, int out_size, void* d_ws, size_t ws_size,
                              hipStream_t stream)
{
    const float* features     = (const float*)d_in[0];
    const int*   labels       = (const int*)  d_in[1];
    const float* queue        = (const float*)d_in[2];
    const int*   queue_labels = (const int*)  d_in[3];
    char* ws = (char*)d_ws;

    const size_t qbf_sz   = (size_t)QQ * DD * 2;   // 16 MB
    const size_t f2bf_sz  = (size_t)BB * DD * 2;   // 256 KB
    const size_t qlabn_sz = (size_t)QQ * 4;        // 256 KB
    const size_t fsum_sz  = (size_t)1024 * DD * 4; // 512 KB
    const size_t cnt_sz   = 4096;
    const size_t srr_sz   = 4096;
    const size_t scal_sz  = 256;
    const size_t tail_sz  = fsum_sz + cnt_sz + srr_sz + scal_sz;

    int nslices = NSLICES;
    size_t stats_sz = (size_t)BB * nslices * 2 * sizeof(float);
    bool pre = ws_size >= qbf_sz + f2bf_sz + qlabn_sz + stats_sz + tail_sz;
    if (!pre) {
        while ((size_t)BB * nslices * 2 * sizeof(float) + tail_sz > ws_size && nslices > 8)
            nslices >>= 1;
        stats_sz = (size_t)BB * nslices * 2 * sizeof(float);
    }

    size_t off = 0;
    unsigned short* qbf = nullptr; unsigned short* f2bf = nullptr; int* qlabn = nullptr;
    if (pre) {
        qbf   = (unsigned short*)(ws + off); off += qbf_sz;
        f2bf  = (unsigned short*)(ws + off); off += f2bf_sz;
        qlabn = (int*)(ws + off);            off += qlabn_sz;
    }
    float* stats = (float*)(ws + off); off += stats_sz;
    float* fsum  = (float*)(ws + off); off += fsum_sz;
    int*   cnt   = (int*)(ws + off);   off += cnt_sz;
    float* srr   = (float*)(ws + off); off += srr_sz;
    float* scal  = (float*)(ws + off); // [0]=S1, [1]=accT, [2]=accP

    hipMemsetAsync((void*)fsum, 0, tail_sz, stream);

    k0_prep<<<dim3(256), dim3(256), 0, stream>>>(
        features, labels, queue_labels, fsum, cnt, srr, f2bf);

    if (pre)
        k1_gather<1><<<dim3(256), dim3(256), 0, stream>>>(
            features, labels, queue, queue_labels, fsum, cnt, qbf, qlabn, scal);
    else
        k1_gather<0><<<dim3(256), dim3(256), 0, stream>>>(
            features, labels, queue, queue_labels, fsum, cnt, qbf, qlabn, scal);

    dim3 grid(F2G * nslices);
    if (pre)
        supcon_main<1><<<grid, dim3(THREADS), 0, stream>>>(
            features, labels, queue, queue_labels, qbf, qlabn, f2bf, stats, nslices);
    else
        supcon_main<0><<<grid, dim3(THREADS), 0, stream>>>(
            features, labels, queue, queue_labels, qbf, qlabn, f2bf, stats, nslices);

    f1_rows<<<dim3(BB / 4), dim3(256), 0, stream>>>(stats, srr, cnt, labels, scal + 1, nslices);
    f2_out<<<dim3(1), dim3(64), 0, stream>>>(scal + 1, scal, (float*)d_out);
}